// Round 12
// baseline (555.343 us; speedup 1.0000x reference)
//
#include <hip/hip_runtime.h>

// RadarRnn1: 4-layer tanh RNN (B=512,S=1024,IN=64,H=32) + per-step FC + softmax over S.
// R20: R19's fusion solved the residue mystery (single kernel; 129us fixed
// harness overhead + 282.7us kernel) but the 8-wave structure cost +62us vs
// the 4-wave rnn (220us): 8-wave barrier rendezvous + SIMD sharing. Fix: fold
// u0 production into waves 1-3's measured slack (~3200cy/window vs ~1200cy of
// production), restoring the proven 4-wave/256-thread block:
//   - wave w (1..3) produces u0 ticks i=(w-1)+3q (q=0..5, i<16) of block n+1
//     into lu0[(n+1)&1] at the END of iteration n; block 0 pre-loop. Same ring
//     parity + lgkmcnt-drain safety as R19; same dpp cross-ks f32 numerics
//     (absmax 0.00390625 held in R19).
//   - wave 0 unchanged (reads lu0[n&1], FC duty balances production).
//   - softmax epilogue back to the unguarded 256-thread bit-identical form.
// Pipeline structure byte-equivalent to R16/R19 elsewhere.

#define BB 512
#define SS 1024
#define INF 64
#define HH 32
#define LL 4
#define KB 16  // ticks per barrier iteration

typedef __fp16 v2h __attribute__((ext_vector_type(2)));

__device__ __forceinline__ v2h bch(unsigned u) { return __builtin_bit_cast(v2h, u); }
__device__ __forceinline__ unsigned bcu(v2h h) { return __builtin_bit_cast(unsigned, h); }

template <int CTRL>
__device__ __forceinline__ float dpp_add(float v) {
  int y = __builtin_amdgcn_update_dpp(0, __float_as_int(v), CTRL, 0xF, 0xF, true);
  return v + __int_as_float(y);
}
template <int CTRL>
__device__ __forceinline__ float dpp_mov(float v) {
  int y = __builtin_amdgcn_update_dpp(0, __float_as_int(v), CTRL, 0xF, 0xF, true);
  return __int_as_float(y);
}

// tanh(a) = 1 - 2/(e^{2a}+1); e^{2a} = 2^(a * 2/ln2). v_exp + v_rcp + fma.
__device__ __forceinline__ float tanh_fast(float a) {
  const float e = __builtin_amdgcn_exp2f(a * 2.885390081777927f);
  const float r = __builtin_amdgcn_rcpf(e + 1.0f);
  return __builtin_fmaf(-2.0f, r, 1.0f);
}

// 16-half dot (ks-half): 8 fdot2 in 2 chains of depth 4.
__device__ __forceinline__ float dot16p(const v2h* w, const v2h* v) {
  float a = 0.f, c = 0.f;
#pragma unroll
  for (int j = 0; j < 4; ++j) {
    a = __builtin_amdgcn_fdot2(w[2 * j + 0], v[2 * j + 0], a, false);
    c = __builtin_amdgcn_fdot2(w[2 * j + 1], v[2 * j + 1], c, false);
  }
  return a + c;
}

// lgkmcnt-only barrier: drains LDS ops (cross-wave handoff) but leaves global
// loads/stores in flight (x loads, hfin stores).
#define BAR() asm volatile("s_waitcnt lgkmcnt(0)\n\ts_barrier" ::: "memory")

// ---------------- fused kernel: 4 waves, pipeline + in-slack u0 production ----------------
__global__ __launch_bounds__(256, 2) void rnn_kernel(
    const float* __restrict__ x, const float* __restrict__ h_state,
    const float* __restrict__ W_ih0, const float* __restrict__ W_ih_rest,
    const float* __restrict__ W_hh, const float* __restrict__ b_ih,
    const float* __restrict__ b_hh, const float* __restrict__ fc_w,
    const float* __restrict__ fc_b, float* __restrict__ out) {
  __shared__ int hb[LL][2][KB][16];  // [layer][buf=n&1][i][pair] f16x2
  __shared__ float h3f[2][KB][32];   // [buf][i][unit]: wave3's f32 hv for FC
  __shared__ float lu0[2][KB][32];   // [buf][i][unit]: u0 ring
  __shared__ float lrow[SS];         // full logit row (4KB), softmaxed at the end
  __shared__ float red[8];           // softmax cross-wave reduce

  const int tid  = threadIdx.x;
  const int wid  = tid >> 6;   // wave id == layer id
  const int lane = tid & 63;
  const int b    = blockIdx.x; // one batch element per block
  const int ks   = lane & 1;   // k-split half
  const int h    = lane >> 1;  // output unit 0..31

  // pipeline weights: f16-packed h-matrices (x-part of layer 0 = u0)
  v2h wih[8], whh[8];
  {
    const float2* ph = (const float2*)(W_hh + (size_t)(wid * HH + h) * HH + ks * 16);
#pragma unroll
    for (int j = 0; j < 8; ++j) whh[j] = __builtin_amdgcn_cvt_pkrtz(ph[j].x, ph[j].y);
  }
  float bias = 0.f;  // layer 0 bias folded into u0
  if (wid > 0) {
    const float2* pi =
        (const float2*)(W_ih_rest + (size_t)((wid - 1) * HH + h) * HH + ks * 16);
#pragma unroll
    for (int j = 0; j < 8; ++j) wih[j] = __builtin_amdgcn_cvt_pkrtz(pi[j].x, pi[j].y);
  }
  // producer weights (waves 1-3): f32 W_ih0 half-row (preserves u0 f32 numerics)
  float4 wv4[8];
  float bias0 = 0.f;
  if (wid > 0) {
    const float4* wr = (const float4*)(W_ih0 + (size_t)h * INF + ks * 32);
#pragma unroll
    for (int j = 0; j < 8; ++j) wv4[j] = wr[j];
    bias0 = b_ih[h] + b_hh[h];
    bias = b_ih[wid * HH + h] + b_hh[wid * HH + h];
  }
  const float fcwh = fc_w[h] * 0.5f;  // both ks lanes hold hv -> 64-lane sum is 2x
  const float fcb  = fc_b[0];

  // own h(-1) straight into registers (packed ks-half)
  v2h sv[8];
  {
    const float2* hs = (const float2*)(h_state + (size_t)(wid * BB + b) * HH);
#pragma unroll
    for (int j = 0; j < 8; ++j)
      sv[j] = __builtin_amdgcn_cvt_pkrtz(hs[ks * 8 + j].x, hs[ks * 8 + j].y);
  }

  const float* xb = x + (size_t)b * SS * INF;
  float* const hfin = out + (size_t)BB * SS;

  auto ld8 = [&](const int* p, v2h* v) __attribute__((always_inline)) {
    const uint4* q = (const uint4*)p;
    uint4 A = q[0], B = q[1];
    v[0] = bch(A.x); v[1] = bch(A.y); v[2] = bch(A.z); v[3] = bch(A.w);
    v[4] = bch(B.x); v[5] = bch(B.y); v[6] = bch(B.z); v[7] = bch(B.w);
  };
  auto packpair = [&](float hv) __attribute__((always_inline)) {
    return bcu(__builtin_amdgcn_cvt_pkrtz(hv, dpp_mov<0xEE>(hv)));
  };
  auto store_pk = [&](int l, int buf, int slot, unsigned pk) __attribute__((always_inline)) {
    if ((lane & 3) == 0) hb[l][buf][slot][lane >> 2] = (int)pk;
  };
  auto fcred = [&](float v) __attribute__((always_inline)) {
    v = dpp_add<0x111>(v);  // row_shr:1
    v = dpp_add<0x112>(v);  // row_shr:2
    v = dpp_add<0x114>(v);  // row_shr:4
    v = dpp_add<0x118>(v);  // row_shr:8
    v = dpp_add<0x142>(v);  // row_bcast:15
    v = dpp_add<0x143>(v);  // row_bcast:31
    return v;               // lane 63 holds the 64-lane sum
  };
  // u0 production (waves 1-3): wave w covers ticks i=(w-1)+3q of block blk.
  auto produce = [&](int blk) __attribute__((always_inline)) {
    const int buf = blk & 1;
    const int T = KB * blk;
#pragma unroll
    for (int q = 0; q < 6; ++q) {
      const int i = (wid - 1) + 3 * q;
      if (i < KB) {  // wave-uniform (wid uniform per wave)
        const float4* x4 = (const float4*)(xb + (size_t)(T + i) * INF + ks * 32);
        float acc = 0.f;
#pragma unroll
        for (int j = 0; j < 8; ++j) {
          const float4 xv = x4[j];
          acc += wv4[j].x * xv.x + wv4[j].y * xv.y + wv4[j].z * xv.z + wv4[j].w * xv.w;
        }
        const float tot = dpp_add<0xB1>(acc) + bias0;  // cross-ks combine
        if (ks == 0) lu0[buf][i][h] = tot;  // 32 consec addrs, conflict-free
      }
    }
  };

  // Schedule (68 barrier-iterations): wave l computes tick block 16(n-l)..+15
  // at iteration n (active l<=n<=63+l), exactly as R16/R19. Waves 1-3 also
  // produce u0 block n+1 into lu0[(n+1)&1] at the end of iteration n (n<=62);
  // block 0 pre-loop (published by BAR(0)). Wave 0 reads lu0[n&1]; its reads
  // drain at its own lgkmcnt(0) before BAR(n+1), and producers write that buf
  // only after BAR(n+1) -> proven ring discipline.
  if (wid == 0) {
    for (int n = 0; n < 68; ++n) {
      BAR();
      const int buf = n & 1;
      const bool fc_on = (n >= 4);
      const bool cw    = (n <= 63);
      float a[KB];
      if (fc_on) {
#pragma unroll
        for (int i = 0; i < KB; ++i) a[i] = h3f[buf ^ 1][i][h];
      }
      if (cw) {
        float ur[KB];
#pragma unroll
        for (int i = 0; i < KB; ++i) ur[i] = lu0[buf][i][h];  // conflict-free b32
        float hvL = 0.f;
#pragma unroll
        for (int i = 0; i < KB; ++i) {
          float acc = dot16p(whh, sv);
          acc = dpp_add<0xB1>(acc) + ur[i];  // u0 holds x-part + full bias0
          const float hv = tanh_fast(acc);
          const unsigned pk = packpair(hv);
          store_pk(0, buf, i, pk);
          ld8(&hb[0][buf][i][ks * 8], sv);   // own carry (in-order DS RAW)
          if (i == KB - 1) hvL = hv;
        }
        if (n == 63 && ks == 0) hfin[(0 * BB + b) * HH + h] = hvL;
      }
      if (fc_on) {  // FC for wave3's block from iter n-1: t = 16(n-4)+i
        const int tf0 = KB * (n - 4);
#pragma unroll
        for (int i = 0; i < KB; ++i) {
          float v = fcred(a[i] * fcwh);
          if (lane == 63) lrow[tf0 + i] = v + fcb;
        }
      }
    }
  } else {
    v2h viA[4][8], viB[4][8];  // input groups of 4 ticks, double-banked
    auto ldgrp = [&](int buf, int g, v2h (*vv)[8]) __attribute__((always_inline)) {
#pragma unroll
      for (int q = 0; q < 4; ++q)
        ld8(&hb[wid - 1][buf ^ 1][g * 4 + q][ks * 8], vv[q]);
    };
    auto dogrp = [&](int n, int buf, int g, v2h (*vc)[8], float& hvL)
        __attribute__((always_inline)) {
#pragma unroll
      for (int q = 0; q < 4; ++q) {
        const int i = g * 4 + q;
        float accA = dot16p(wih, vc[q]);      // independent: overlaps carry wait
        float acc = accA + dot16p(whh, sv);
        acc = dpp_add<0xB1>(acc) + bias;
        const float hv = tanh_fast(acc);
        const unsigned pk = packpair(hv);
        store_pk(wid, buf, i, pk);
        if (wid == 3 && ks == 0) h3f[buf][i][h] = hv;  // f32 handoff to FC
        ld8(&hb[wid][buf][i][ks * 8], sv);             // own carry
        if (i == KB - 1) hvL = hv;
      }
    };
    produce(0);  // block 0 pre-loop; published by BAR(0)
    auto iterl = [&](int n, int buf) __attribute__((always_inline)) {
      BAR();
      const bool cw = (n >= wid && n <= 63 + wid);
      if (cw) {
        float hvL = 0.f;
        ldgrp(buf, 0, viA);
        ldgrp(buf, 1, viB);          // prefetch group 1
        dogrp(n, buf, 0, viA, hvL);
        ldgrp(buf, 2, viA);          // prefetch group 2 (viA free)
        dogrp(n, buf, 1, viB, hvL);
        ldgrp(buf, 3, viB);          // prefetch group 3 (viB free)
        dogrp(n, buf, 2, viA, hvL);
        dogrp(n, buf, 3, viB, hvL);
        if (n == 63 + wid && ks == 0) hfin[(wid * BB + b) * HH + h] = hvL;
      }
      if (n <= 62) produce(n + 1);   // in-slack u0 production for next block
    };
    for (int n0 = 0; n0 < 68; n0 += 2) {
      iterl(n0, 0);
      iterl(n0 + 1, 1);
    }
  }

  // ---- fused softmax over lrow (exact replica of the proven softmax) ----
  __syncthreads();  // all lrow writes visible to all waves
  {
    float4 v = ((const float4*)lrow)[tid];  // 256 threads x 4 = 1024 logits
    float m = fmaxf(fmaxf(v.x, v.y), fmaxf(v.z, v.w));
#pragma unroll
    for (int d = 32; d >= 1; d >>= 1) m = fmaxf(m, __shfl_xor(m, d));
    if ((tid & 63) == 0) red[tid >> 6] = m;
    __syncthreads();
    m = fmaxf(fmaxf(red[0], red[1]), fmaxf(red[2], red[3]));
    const float e0 = __expf(v.x - m), e1 = __expf(v.y - m);
    const float e2 = __expf(v.z - m), e3 = __expf(v.w - m);
    float s = (e0 + e1) + (e2 + e3);
#pragma unroll
    for (int d = 32; d >= 1; d >>= 1) s += __shfl_xor(s, d);
    if ((tid & 63) == 0) red[4 + (tid >> 6)] = s;
    __syncthreads();
    s = (red[4] + red[5]) + (red[6] + red[7]);
    const float inv = 1.0f / s;
    float4 o;
    o.x = e0 * inv; o.y = e1 * inv; o.z = e2 * inv; o.w = e3 * inv;
    ((float4*)(out + (size_t)b * SS))[tid] = o;
  }
}

extern "C" void kernel_launch(void* const* d_in, const int* in_sizes, int n_in,
                              void* d_out, int out_size, void* d_ws, size_t ws_size,
                              hipStream_t stream) {
  const float* x         = (const float*)d_in[0];
  const float* h_state   = (const float*)d_in[1];
  const float* W_ih0     = (const float*)d_in[2];
  const float* W_ih_rest = (const float*)d_in[3];
  const float* W_hh      = (const float*)d_in[4];
  const float* b_ih      = (const float*)d_in[5];
  const float* b_hh      = (const float*)d_in[6];
  const float* fc_w      = (const float*)d_in[7];
  const float* fc_b      = (const float*)d_in[8];
  float* out = (float*)d_out;

  hipLaunchKernelGGL(rnn_kernel, dim3(BB), dim3(256), 0, stream,
                     x, h_state, W_ih0, W_ih_rest, W_hh, b_ih, b_hh,
                     fc_w, fc_b, out);
}